// Round 4
// baseline (360.294 us; speedup 1.0000x reference)
//
#include <hip/hip_runtime.h>

// (B,C,H,W) = (8,21,512,512), gamma = 2.0
#define CCH    21
#define HWSZ   (512*512)          // 2^18
#define HW4    (HWSZ/4)           // 2^16 float4 groups per plane
#define NPIX   (8*HWSZ)           // 2097152
#define BLKT   256
#define NBLK   (NPIX/4/BLKT)      // 2048 blocks, one float4 (4 pixels) per thread
#define PF     4                  // channel pipeline depth (ring buffer)

// s_waitcnt imm: lgkmcnt=15 (don't care), expcnt=7 (don't care), vmcnt=N
// builtin arg must be a frontend literal constant.
#define WAIT_VM(n) __builtin_amdgcn_s_waitcnt(0x0F70 | (n))

typedef float vfloat4 __attribute__((ext_vector_type(4)));

// ---------------------------------------------------------------------------
// Kernel 1: single-pass focal term, HIGH-OCCUPANCY register streaming.
// R11 = R8 structure with the ring-buffer clobber FIXED.
// R9/R10 bug (identical absmax 4.887581e-06 both rounds -> deterministic):
//   pv[(c+PF)%PF] = load(c+PF) writes the SAME slot as pv[c%PF], BEFORE the
//   consume read -> consume saw channel c+3's data; channels 0-2 dropped,
//   18-20 double-counted, class labels off by 3. C-semantics bug, not a race.
// Fix: wait(pair c) -> copy slot to locals (free, SSA renaming) -> refill
// slot with channel c+PF -> math. Read-before-write in source order.
// Structure theory unchanged: V0's 3.37 TB/s plateau was structural (57KB
// LDS -> 8 waves/CU + block churn). Here: ~200 B LDS, whole grid
// co-resident, 2 streams/wave depth-4, vmcnt(6) steady-state fence.
// NUMERICS: p_y from tracked exp (p = ey/s), V0's exact path.
// No max-subtraction: logits are N(0,1), fp32 exp cannot overflow.
// ---------------------------------------------------------------------------
__global__ __launch_bounds__(BLKT) void cb_focal_partial(
    const float* __restrict__ pred, const float* __restrict__ targ,
    float* __restrict__ gsum, float* __restrict__ gcnt)
{
    __shared__ float ls_sum[CCH];
    __shared__ float ls_cnt[CCH];
    if (threadIdx.x < CCH) { ls_sum[threadIdx.x] = 0.f; ls_cnt[threadIdx.x] = 0.f; }
    __syncthreads();

    const int tid = blockIdx.x * BLKT + threadIdx.x;   // 0 .. 524287
    const int b   = tid >> 16;                         // / HW4
    const int hw4 = tid & (HW4 - 1);
    const float* pp = pred + (size_t)b * CCH * HWSZ + (size_t)hw4 * 4;
    const float* tp = targ + (size_t)b * CCH * HWSZ + (size_t)hw4 * 4;

    float s0 = 0.f, s1 = 0.f, s2 = 0.f, s3 = 0.f;
    float vy0 = 0.f, vy1 = 0.f, vy2 = 0.f, vy3 = 0.f;
    float ey0 = 1.f, ey1 = 1.f, ey2 = 1.f, ey3 = 1.f;
    int   y0 = 0, y1 = 0, y2 = 0, y3 = 0;

    vfloat4 pv[PF], tv[PF];                            // register ring buffer

    // ---- prologue: channels 0..PF-1 in flight, pair order pinned ----
    #pragma unroll
    for (int c = 0; c < PF; ++c) {
        pv[c] = *(const vfloat4*)(pp + (size_t)c * HWSZ);
        tv[c] = *(const vfloat4*)(tp + (size_t)c * HWSZ);
        __builtin_amdgcn_sched_barrier(0);             // keep FIFO pair order
    }

    #pragma unroll
    for (int c = 0; c < CCH; ++c) {
        // in-flight at entry: pairs {c .. min(c+PF-1, CCH-1)}.
        // Drain pair c only; newer pairs stay in flight.
        if      (c <= CCH - 4) { WAIT_VM(6); }
        else if (c == CCH - 3) { WAIT_VM(4); }
        else if (c == CCH - 2) { WAIT_VM(2); }
        else                   { WAIT_VM(0); }
        __builtin_amdgcn_sched_barrier(0);

        // grab slot c%PF (channel c) BEFORE refilling it
        const vfloat4 p = pv[c % PF];
        const vfloat4 t = tv[c % PF];

        // refill slot with channel c+PF (issued before the exp math)
        if (c + PF < CCH) {
            pv[c % PF] = *(const vfloat4*)(pp + (size_t)(c + PF) * HWSZ);
            tv[c % PF] = *(const vfloat4*)(tp + (size_t)(c + PF) * HWSZ);
        }
        __builtin_amdgcn_sched_barrier(0);

        // ---- consume channel c ----
        const float e0 = __expf(p.x), e1 = __expf(p.y),
                    e2 = __expf(p.z), e3 = __expf(p.w);
        s0 += e0; s1 += e1; s2 += e2; s3 += e3;
        const bool h0 = t.x > 0.5f, h1 = t.y > 0.5f,
                   h2 = t.z > 0.5f, h3 = t.w > 0.5f;
        y0 = h0 ? c : y0;  vy0 = h0 ? p.x : vy0;  ey0 = h0 ? e0 : ey0;
        y1 = h1 ? c : y1;  vy1 = h1 ? p.y : vy1;  ey1 = h1 ? e1 : ey1;
        y2 = h2 ? c : y2;  vy2 = h2 ? p.z : vy2;  ey2 = h2 ? e2 : ey2;
        y3 = h3 ? c : y3;  vy3 = h3 ? p.w : vy3;  ey3 = h3 ? e3 : ey3;
    }

    // rv = (1 - p_y)^2 * log p_y ;  p_y = e_y / s ;  log p_y = v_y - log s
    {
        const float l0 = vy0 - __logf(s0), p0 = ey0 / s0, o0 = 1.f - p0;
        const float l1 = vy1 - __logf(s1), p1 = ey1 / s1, o1 = 1.f - p1;
        const float l2 = vy2 - __logf(s2), p2 = ey2 / s2, o2 = 1.f - p2;
        const float l3 = vy3 - __logf(s3), p3 = ey3 / s3, o3 = 1.f - p3;
        atomicAdd(&ls_sum[y0], o0 * o0 * l0);  atomicAdd(&ls_cnt[y0], 1.f);
        atomicAdd(&ls_sum[y1], o1 * o1 * l1);  atomicAdd(&ls_cnt[y1], 1.f);
        atomicAdd(&ls_sum[y2], o2 * o2 * l2);  atomicAdd(&ls_cnt[y2], 1.f);
        atomicAdd(&ls_sum[y3], o3 * o3 * l3);  atomicAdd(&ls_cnt[y3], 1.f);
    }
    __syncthreads();
    if (threadIdx.x < CCH) {
        atomicAdd(&gsum[threadIdx.x], ls_sum[threadIdx.x]);
        atomicAdd(&gcnt[threadIdx.x], ls_cnt[threadIdx.x]);
    }
}

// ---------------------------------------------------------------------------
// Kernel 2: one wave. Class-balanced weights + final scalar, in double.
// ---------------------------------------------------------------------------
__global__ void cb_focal_final(const float* __restrict__ gsum,
                               const float* __restrict__ gcnt,
                               float* __restrict__ out)
{
    const int lane = threadIdx.x;
    double term = 0.0;
    if (lane < CCH) {
        const double n    = (double)NPIX;
        const double beta = (n - 1.0) / n;
        const double w = (1.0 - beta) / (1.0 - pow(beta, (double)gcnt[lane]) + 1e-6);
        term = w * (double)gsum[lane];
    }
    for (int off = 32; off; off >>= 1) term += __shfl_down(term, off, 64);
    if (lane == 0) out[0] = (float)(-term / (double)NPIX);
}

// ---------------------------------------------------------------------------
extern "C" void kernel_launch(void* const* d_in, const int* in_sizes, int n_in,
                              void* d_out, int out_size, void* d_ws, size_t ws_size,
                              hipStream_t stream) {
    const float* pred = (const float*)d_in[0];
    const float* targ = (const float*)d_in[1];
    float* out  = (float*)d_out;
    float* gsum = (float*)d_ws;          // [21]
    float* gcnt = gsum + CCH;            // [21]

    (void)hipMemsetAsync(gsum, 0, 2 * CCH * sizeof(float), stream);
    cb_focal_partial<<<NBLK, BLKT, 0, stream>>>(pred, targ, gsum, gcnt);
    cb_focal_final<<<1, 64, 0, stream>>>(gsum, gcnt, out);
}

// Round 5
// 355.597 us; speedup vs baseline: 1.0132x; 1.0132x over previous
//
#include <hip/hip_runtime.h>

// (B,C,H,W) = (8,21,512,512), gamma = 2.0
#define CCH    21
#define HWSZ   (512*512)          // 2^18
#define HW4    (HWSZ/4)           // 2^16 float4 groups per plane
#define NPIX   (8*HWSZ)           // 2097152
#define BLKT   256
#define NBLK   (NPIX/4/BLKT)      // 2048 blocks, one float4 (4 pixels) per thread
#define CS     3                  // channels per pipeline step
#define NS     7                  // steps (7*3 = 21)

// s_waitcnt imms (gfx9 field layout: vmcnt[3:0]+[15:14], expcnt[6:4], lgkmcnt[11:8])
#define WAIT_VM0   __builtin_amdgcn_s_waitcnt(0x0F70)   // vmcnt(0), rest don't-care
#define WAIT_LGKM0 __builtin_amdgcn_s_waitcnt(0xC07F)   // lgkmcnt(0), rest don't-care

typedef float vfloat4 __attribute__((ext_vector_type(4)));

// async global->LDS, 16 B per lane; LDS dest is wave-uniform base + lane*16
__device__ __forceinline__ void stage16(const float* g, vfloat4* l) {
    __builtin_amdgcn_global_load_lds(
        (const __attribute__((address_space(1))) unsigned int*)g,
        (__attribute__((address_space(3))) unsigned int*)l, 16, 0, 0);
}

// ---------------------------------------------------------------------------
// Kernel 1: single-pass focal term — DUAL-PATH at HIGH OCCUPANCY.
// Post-mortem trail:
//   V0  (dual-path, 57KB LDS, 8 waves/CU, churn):      104.5 us = 3.37 TB/s
//   R11 (single-path regs, ~0 LDS, 54% occ, no churn): 125.5 us = 2.82 TB/s
// -> Occupancy is NOT the lever (R11 falsified that); the VGPR-return read
//    path caps ~2.8 TB/s regardless of waves/depth. V0's +20% came from the
//    dual path: pred via nt register loads, targ via global_load_lds (LDS
//    direct-write). R12 keeps the dual path but shrinks staging to a
//    3-channel SINGLE buffer (12 KB): 7 steps x 3 channels, vmcnt(0) drain
//    per step, lgkmcnt(0) between ds_read-back and DMA re-issue (WAW on the
//    same slots; wave-local slices, no __syncthreads in the loop).
//    12 KB -> 8 blocks/CU -> full grid co-resident WITH dual path engaged.
// NUMERICS: V0's exact path (p_y from tracked exp, p = ey/s). No
// max-subtraction: logits are N(0,1), fp32 exp cannot overflow.
// ---------------------------------------------------------------------------
__global__ __launch_bounds__(BLKT) void cb_focal_partial(
    const float* __restrict__ pred, const float* __restrict__ targ,
    float* __restrict__ gsum, float* __restrict__ gcnt)
{
    __shared__ vfloat4 tbuf[CS][BLKT];   // 3*256*16 B = 12 KB, per-wave slices
    __shared__ float ls_sum[CCH];
    __shared__ float ls_cnt[CCH];
    if (threadIdx.x < CCH) { ls_sum[threadIdx.x] = 0.f; ls_cnt[threadIdx.x] = 0.f; }
    __syncthreads();

    const int tid = blockIdx.x * BLKT + threadIdx.x;   // 0 .. 524287
    const int b   = tid >> 16;                         // / HW4
    const int hw4 = tid & (HW4 - 1);
    const float* pp = pred + (size_t)b * CCH * HWSZ + (size_t)hw4 * 4;
    const float* tp = targ + (size_t)b * CCH * HWSZ + (size_t)hw4 * 4;
    const int wv = threadIdx.x & 192;                  // wave base: 0,64,128,192

    float s0 = 0.f, s1 = 0.f, s2 = 0.f, s3 = 0.f;
    float vy0 = 0.f, vy1 = 0.f, vy2 = 0.f, vy3 = 0.f;
    float ey0 = 1.f, ey1 = 1.f, ey2 = 1.f, ey3 = 1.f;
    int   y0 = 0, y1 = 0, y2 = 0, y3 = 0;

    vfloat4 pn[CS];                                    // pred lookahead regs

    // ---- prologue: step 0 in flight (3 DMA + 3 nt reg loads) ----
    #pragma unroll
    for (int j = 0; j < CS; ++j)
        stage16(tp + (size_t)j * HWSZ, &tbuf[j][wv]);
    #pragma unroll
    for (int j = 0; j < CS; ++j)
        pn[j] = __builtin_nontemporal_load((const vfloat4*)(pp + (size_t)j * HWSZ));
    __builtin_amdgcn_sched_barrier(0);

    #pragma unroll
    for (int s = 0; s < NS; ++s) {
        // step s's 6 VMEM ops (3 DMA + 3 reg) are the only ones in flight
        WAIT_VM0;
        __builtin_amdgcn_sched_barrier(0);

        // grab pred regs (SSA rename) and read targ slices out of LDS
        vfloat4 pv[CS], tv[CS];
        #pragma unroll
        for (int j = 0; j < CS; ++j) pv[j] = pn[j];
        #pragma unroll
        for (int j = 0; j < CS; ++j) tv[j] = tbuf[j][threadIdx.x];
        WAIT_LGKM0;                      // ds_reads done -> slots reusable
        __builtin_amdgcn_sched_barrier(0);

        // issue step s+1 into the SAME slots (wave-local, reads complete)
        if (s + 1 < NS) {
            #pragma unroll
            for (int j = 0; j < CS; ++j)
                stage16(tp + (size_t)((s + 1) * CS + j) * HWSZ, &tbuf[j][wv]);
            #pragma unroll
            for (int j = 0; j < CS; ++j)
                pn[j] = __builtin_nontemporal_load(
                    (const vfloat4*)(pp + (size_t)((s + 1) * CS + j) * HWSZ));
        }
        __builtin_amdgcn_sched_barrier(0);

        // ---- consume step s (3 channels) ----
        #pragma unroll
        for (int j = 0; j < CS; ++j) {
            const int c = s * CS + j;
            const vfloat4 p = pv[j];
            const vfloat4 t = tv[j];
            const float e0 = __expf(p.x), e1 = __expf(p.y),
                        e2 = __expf(p.z), e3 = __expf(p.w);
            s0 += e0; s1 += e1; s2 += e2; s3 += e3;
            const bool h0 = t.x > 0.5f, h1 = t.y > 0.5f,
                       h2 = t.z > 0.5f, h3 = t.w > 0.5f;
            y0 = h0 ? c : y0;  vy0 = h0 ? p.x : vy0;  ey0 = h0 ? e0 : ey0;
            y1 = h1 ? c : y1;  vy1 = h1 ? p.y : vy1;  ey1 = h1 ? e1 : ey1;
            y2 = h2 ? c : y2;  vy2 = h2 ? p.z : vy2;  ey2 = h2 ? e2 : ey2;
            y3 = h3 ? c : y3;  vy3 = h3 ? p.w : vy3;  ey3 = h3 ? e3 : ey3;
        }
    }

    // rv = (1 - p_y)^2 * log p_y ;  p_y = e_y / s ;  log p_y = v_y - log s
    {
        const float l0 = vy0 - __logf(s0), p0 = ey0 / s0, o0 = 1.f - p0;
        const float l1 = vy1 - __logf(s1), p1 = ey1 / s1, o1 = 1.f - p1;
        const float l2 = vy2 - __logf(s2), p2 = ey2 / s2, o2 = 1.f - p2;
        const float l3 = vy3 - __logf(s3), p3 = ey3 / s3, o3 = 1.f - p3;
        atomicAdd(&ls_sum[y0], o0 * o0 * l0);  atomicAdd(&ls_cnt[y0], 1.f);
        atomicAdd(&ls_sum[y1], o1 * o1 * l1);  atomicAdd(&ls_cnt[y1], 1.f);
        atomicAdd(&ls_sum[y2], o2 * o2 * l2);  atomicAdd(&ls_cnt[y2], 1.f);
        atomicAdd(&ls_sum[y3], o3 * o3 * l3);  atomicAdd(&ls_cnt[y3], 1.f);
    }
    __syncthreads();
    if (threadIdx.x < CCH) {
        atomicAdd(&gsum[threadIdx.x], ls_sum[threadIdx.x]);
        atomicAdd(&gcnt[threadIdx.x], ls_cnt[threadIdx.x]);
    }
}

// ---------------------------------------------------------------------------
// Kernel 2: one wave. Class-balanced weights + final scalar, in double.
// ---------------------------------------------------------------------------
__global__ void cb_focal_final(const float* __restrict__ gsum,
                               const float* __restrict__ gcnt,
                               float* __restrict__ out)
{
    const int lane = threadIdx.x;
    double term = 0.0;
    if (lane < CCH) {
        const double n    = (double)NPIX;
        const double beta = (n - 1.0) / n;
        const double w = (1.0 - beta) / (1.0 - pow(beta, (double)gcnt[lane]) + 1e-6);
        term = w * (double)gsum[lane];
    }
    for (int off = 32; off; off >>= 1) term += __shfl_down(term, off, 64);
    if (lane == 0) out[0] = (float)(-term / (double)NPIX);
}

// ---------------------------------------------------------------------------
extern "C" void kernel_launch(void* const* d_in, const int* in_sizes, int n_in,
                              void* d_out, int out_size, void* d_ws, size_t ws_size,
                              hipStream_t stream) {
    const float* pred = (const float*)d_in[0];
    const float* targ = (const float*)d_in[1];
    float* out  = (float*)d_out;
    float* gsum = (float*)d_ws;          // [21]
    float* gcnt = gsum + CCH;            // [21]

    (void)hipMemsetAsync(gsum, 0, 2 * CCH * sizeof(float), stream);
    cb_focal_partial<<<NBLK, BLKT, 0, stream>>>(pred, targ, gsum, gcnt);
    cb_focal_final<<<1, 64, 0, stream>>>(gsum, gcnt, out);
}

// Round 6
// 349.612 us; speedup vs baseline: 1.0306x; 1.0171x over previous
//
#include <hip/hip_runtime.h>

// (B,C,H,W) = (8,21,512,512), gamma = 2.0
#define CCH    21
#define HWSZ   (512*512)          // 2^18
#define HW4    (HWSZ/4)           // 2^16 float4 groups per plane
#define NPIX   (8*HWSZ)           // 2097152
#define BLKT   256
#define NBLK   (NPIX/4/BLKT)      // 2048 blocks, one float4 (4 pixels) per thread
#define CS     3                  // channels per pipeline step
#define NS     7                  // steps (7*3 = 21)

// s_waitcnt imm: lgkmcnt=15 (don't care), expcnt=7 (don't care), vmcnt=N literal
#define WAIT_VM(n) __builtin_amdgcn_s_waitcnt(0x0F70 | (n))
#define WAIT_LGKM0 __builtin_amdgcn_s_waitcnt(0xC07F)   // lgkmcnt(0)

typedef float vfloat4 __attribute__((ext_vector_type(4)));

// async global->LDS, 16 B per lane; LDS dest is wave-uniform base + lane*16
__device__ __forceinline__ void stage16(const float* g, vfloat4* l) {
    __builtin_amdgcn_global_load_lds(
        (const __attribute__((address_space(1))) unsigned int*)g,
        (__attribute__((address_space(3))) unsigned int*)l, 16, 0, 0);
}

// ---------------------------------------------------------------------------
// Kernel 1: single-pass focal term — DUAL-PATH + OVERLAP + HIGH OCCUPANCY.
// Factorial trail (partial-kernel delivered read BW):
//   V0  dual-path, deep overlap vmcnt(14), 57KB LDS, 8 w/CU :  3.37 TB/s (104.5us)
//   R11 reg-only, shallow ring, ~0 LDS, 26 w/CU             :  2.82 TB/s (125.5us)
//   R12 dual-path, FULL vmcnt(0) drain/step, 12KB, 16 w/CU  :  3.10 TB/s (113.5us)
// R13 = the missing cell: dual-path + V0's partial-drain overlap discipline
// (issue batch s+1, WAIT_VM(6) -> batch s+1's 6 ops stay in flight while
// batch s is consumed) + 24KB double buffer -> 6 blocks/CU (~24 waves).
// Steady-state in flight: 12 ops/wave = 288KB/CU outstanding (vs V0 224KB).
// If this doesn't beat V0, three max-different structures agree on a
// ~3.4 TB/s delivered-read ceiling -> declare roofline.
// NUMERICS: V0's exact path (p_y from tracked exp, p = ey/s). No
// max-subtraction: logits are N(0,1), fp32 exp cannot overflow.
// ---------------------------------------------------------------------------
__global__ __launch_bounds__(BLKT) void cb_focal_partial(
    const float* __restrict__ pred, const float* __restrict__ targ,
    float* __restrict__ gsum, float* __restrict__ gcnt)
{
    __shared__ vfloat4 tbuf[2][CS][BLKT];   // 2*3*256*16 B = 24 KB
    __shared__ float ls_sum[CCH];
    __shared__ float ls_cnt[CCH];
    if (threadIdx.x < CCH) { ls_sum[threadIdx.x] = 0.f; ls_cnt[threadIdx.x] = 0.f; }
    __syncthreads();

    const int tid = blockIdx.x * BLKT + threadIdx.x;   // 0 .. 524287
    const int b   = tid >> 16;                         // / HW4
    const int hw4 = tid & (HW4 - 1);
    const float* pp = pred + (size_t)b * CCH * HWSZ + (size_t)hw4 * 4;
    const float* tp = targ + (size_t)b * CCH * HWSZ + (size_t)hw4 * 4;
    const int wv = threadIdx.x & 192;                  // wave base: 0,64,128,192

    float s0 = 0.f, s1 = 0.f, s2 = 0.f, s3 = 0.f;
    float vy0 = 0.f, vy1 = 0.f, vy2 = 0.f, vy3 = 0.f;
    float ey0 = 1.f, ey1 = 1.f, ey2 = 1.f, ey3 = 1.f;
    int   y0 = 0, y1 = 0, y2 = 0, y3 = 0;

    vfloat4 pn[2][CS];                                 // pred double buffer

    // ---- prologue: batch 0 in flight (3 DMA + 3 nt reg loads) ----
    #pragma unroll
    for (int j = 0; j < CS; ++j)
        stage16(tp + (size_t)j * HWSZ, &tbuf[0][j][wv]);
    #pragma unroll
    for (int j = 0; j < CS; ++j)
        pn[0][j] = __builtin_nontemporal_load((const vfloat4*)(pp + (size_t)j * HWSZ));
    __builtin_amdgcn_sched_barrier(0);

    #pragma unroll
    for (int s = 0; s < NS; ++s) {
        // issue batch s+1 FIRST, then drain batch s only (6 newest in flight)
        if (s + 1 < NS) {
            #pragma unroll
            for (int j = 0; j < CS; ++j)
                stage16(tp + (size_t)((s + 1) * CS + j) * HWSZ,
                        &tbuf[(s + 1) & 1][j][wv]);
            #pragma unroll
            for (int j = 0; j < CS; ++j)
                pn[(s + 1) & 1][j] = __builtin_nontemporal_load(
                    (const vfloat4*)(pp + (size_t)((s + 1) * CS + j) * HWSZ));
            __builtin_amdgcn_sched_barrier(0);
            WAIT_VM(6);
        } else {
            __builtin_amdgcn_sched_barrier(0);
            WAIT_VM(0);
        }
        __builtin_amdgcn_sched_barrier(0);

        // grab batch s (regs rename free; LDS -> regs)
        vfloat4 pv[CS], tv[CS];
        #pragma unroll
        for (int j = 0; j < CS; ++j) pv[j] = pn[s & 1][j];
        #pragma unroll
        for (int j = 0; j < CS; ++j) tv[j] = tbuf[s & 1][j][threadIdx.x];
        WAIT_LGKM0;            // ds_reads retired -> buffer reusable next iter
        __builtin_amdgcn_sched_barrier(0);

        // ---- consume batch s (3 channels) ----
        #pragma unroll
        for (int j = 0; j < CS; ++j) {
            const int c = s * CS + j;
            const vfloat4 p = pv[j];
            const vfloat4 t = tv[j];
            const float e0 = __expf(p.x), e1 = __expf(p.y),
                        e2 = __expf(p.z), e3 = __expf(p.w);
            s0 += e0; s1 += e1; s2 += e2; s3 += e3;
            const bool h0 = t.x > 0.5f, h1 = t.y > 0.5f,
                       h2 = t.z > 0.5f, h3 = t.w > 0.5f;
            y0 = h0 ? c : y0;  vy0 = h0 ? p.x : vy0;  ey0 = h0 ? e0 : ey0;
            y1 = h1 ? c : y1;  vy1 = h1 ? p.y : vy1;  ey1 = h1 ? e1 : ey1;
            y2 = h2 ? c : y2;  vy2 = h2 ? p.z : vy2;  ey2 = h2 ? e2 : ey2;
            y3 = h3 ? c : y3;  vy3 = h3 ? p.w : vy3;  ey3 = h3 ? e3 : ey3;
        }
    }

    // rv = (1 - p_y)^2 * log p_y ;  p_y = e_y / s ;  log p_y = v_y - log s
    {
        const float l0 = vy0 - __logf(s0), p0 = ey0 / s0, o0 = 1.f - p0;
        const float l1 = vy1 - __logf(s1), p1 = ey1 / s1, o1 = 1.f - p1;
        const float l2 = vy2 - __logf(s2), p2 = ey2 / s2, o2 = 1.f - p2;
        const float l3 = vy3 - __logf(s3), p3 = ey3 / s3, o3 = 1.f - p3;
        atomicAdd(&ls_sum[y0], o0 * o0 * l0);  atomicAdd(&ls_cnt[y0], 1.f);
        atomicAdd(&ls_sum[y1], o1 * o1 * l1);  atomicAdd(&ls_cnt[y1], 1.f);
        atomicAdd(&ls_sum[y2], o2 * o2 * l2);  atomicAdd(&ls_cnt[y2], 1.f);
        atomicAdd(&ls_sum[y3], o3 * o3 * l3);  atomicAdd(&ls_cnt[y3], 1.f);
    }
    __syncthreads();
    if (threadIdx.x < CCH) {
        atomicAdd(&gsum[threadIdx.x], ls_sum[threadIdx.x]);
        atomicAdd(&gcnt[threadIdx.x], ls_cnt[threadIdx.x]);
    }
}

// ---------------------------------------------------------------------------
// Kernel 2: one wave. Class-balanced weights + final scalar, in double.
// ---------------------------------------------------------------------------
__global__ void cb_focal_final(const float* __restrict__ gsum,
                               const float* __restrict__ gcnt,
                               float* __restrict__ out)
{
    const int lane = threadIdx.x;
    double term = 0.0;
    if (lane < CCH) {
        const double n    = (double)NPIX;
        const double beta = (n - 1.0) / n;
        const double w = (1.0 - beta) / (1.0 - pow(beta, (double)gcnt[lane]) + 1e-6);
        term = w * (double)gsum[lane];
    }
    for (int off = 32; off; off >>= 1) term += __shfl_down(term, off, 64);
    if (lane == 0) out[0] = (float)(-term / (double)NPIX);
}

// ---------------------------------------------------------------------------
extern "C" void kernel_launch(void* const* d_in, const int* in_sizes, int n_in,
                              void* d_out, int out_size, void* d_ws, size_t ws_size,
                              hipStream_t stream) {
    const float* pred = (const float*)d_in[0];
    const float* targ = (const float*)d_in[1];
    float* out  = (float*)d_out;
    float* gsum = (float*)d_ws;          // [21]
    float* gcnt = gsum + CCH;            // [21]

    (void)hipMemsetAsync(gsum, 0, 2 * CCH * sizeof(float), stream);
    cb_focal_partial<<<NBLK, BLKT, 0, stream>>>(pred, targ, gsum, gcnt);
    cb_focal_final<<<1, 64, 0, stream>>>(gsum, gcnt, out);
}